// Round 11
// baseline (781.547 us; speedup 1.0000x reference)
//
#include <hip/hip_runtime.h>

#define BATCH 8192
#define NQ 64          // spatial dim n
#define HID 512
#define DIN 192        // 3*n
#define NT 512         // threads per block (8 waves)
#define SPB1 16        // samples per block, fwd1
#define SPB2 32        // samples per block, fwd23

typedef _Float16 f16;
typedef _Float16 f16x8 __attribute__((ext_vector_type(8)));
typedef _Float16 f16x4 __attribute__((ext_vector_type(4)));
typedef float f32x4 __attribute__((ext_vector_type(4)));

// W2 in MFMA-fragment-major order (pre-swizzled global, coalesced 1KB frag loads)
__device__ f16 g_w2fragT[HID * HID];  // frag for contraction k
__device__ f16 g_w2fragR[HID * HID];  // frag for contraction m
// per-sample forward intermediates
__device__ f16   g_h1[(size_t)BATCH * HID];
__device__ float g_t1[(size_t)BATCH * HID];
__device__ float g_n2h1t1[(size_t)BATCH * HID];
__device__ float g_c[(size_t)BATCH * HID];
__device__ float g_s[(size_t)BATCH * HID];

// ---------------- prep: fragment-major f16 W2 layouts ----------------
__global__ void prep_frag(const float* __restrict__ W2) {
    const int k = blockIdx.x;    // 512
    const int m = threadIdx.x;   // 512
    const f16 v = (f16)W2[k * HID + m];
    g_w2fragT[(size_t)((((m >> 4) * 16 + (k >> 5)) * 64) + ((m & 15) | (((k >> 3) & 3) << 4))) * 8 + (k & 7)] = v;
    g_w2fragR[(size_t)((((k >> 4) * 16 + (m >> 5)) * 64) + ((k & 15) | (((m >> 3) & 3) << 4))) * 8 + (m & 7)] = v;
}

// ---------------- fwd1: layer1 in fp32, batched over samples ----------------
__global__ __launch_bounds__(NT)
void fwd1(const float* __restrict__ x, const float* __restrict__ q,
          const float* __restrict__ p, const float* __restrict__ W1,
          const float* __restrict__ b1) {
    __shared__ float zs[SPB1][DIN];
    const int b0 = blockIdx.x * SPB1;
    const int tid = threadIdx.x;
    for (int i = tid; i < SPB1 * DIN; i += NT) {
        const int s = i / DIN, kk = i % DIN;
        float v;
        if (kk < NQ)          v = x[(b0 + s) * NQ + kk];
        else if (kk < 2 * NQ) v = q[(b0 + s) * NQ + kk - NQ];
        else                  v = p[(b0 + s) * NQ + kk - 2 * NQ];
        zs[s][kk] = v;
    }
    __syncthreads();
    const int m = tid;
    float acc[SPB1];
    #pragma unroll
    for (int s = 0; s < SPB1; ++s) acc[s] = 0.f;
    #pragma unroll 2
    for (int k = 0; k < DIN; ++k) {
        const float w = W1[k * HID + m];
        #pragma unroll
        for (int s = 0; s < SPB1; ++s) acc[s] += zs[s][k] * w;
    }
    const float bb = b1[m];
    #pragma unroll
    for (int s = 0; s < SPB1; ++s) {
        const float h1 = tanhf(acc[s] + bb);
        const float t1 = 1.f - h1 * h1;
        const size_t idx = (size_t)(b0 + s) * HID + m;
        g_h1[idx] = (f16)h1;
        g_t1[idx] = t1;
        g_n2h1t1[idx] = -2.f * h1 * t1;
    }
}

// ---------------- fwd23: H2/v2/c then U = V2@W2^T, s — fused ----------------
__global__ __launch_bounds__(NT)
void fwd23(const float* __restrict__ b2, const float* __restrict__ W3) {
    __shared__ f16 alds[SPB2 * HID];
    const int b0 = blockIdx.x * SPB2;
    const int tid = threadIdx.x, lane = tid & 63, wv = tid >> 6;
    const int l15 = lane & 15, qd = lane >> 4;
    const int n0 = wv * 64;

    {
        const int s = tid >> 4;
        f16x8* a8 = (f16x8*)alds;
        #pragma unroll
        for (int c = 0; c < 4; ++c) {
            const int kc = (tid & 15) + c * 16;
            const f16x8 v = *(const f16x8*)&g_h1[(size_t)(b0 + s) * HID + kc * 8];
            a8[s * 64 + (kc ^ (s & 7))] = v;
        }
    }
    __syncthreads();

    const f16x8* a8 = (const f16x8*)alds;
    auto aload = [&](f16x8* AF, int kn) {
        #pragma unroll
        for (int jt = 0; jt < 2; ++jt) {
            const int row = jt * 16 + l15;
            AF[jt] = a8[row * 64 + ((kn * 4 + qd) ^ (row & 7))];
        }
    };
    auto bloadT = [&](f16x8* BF, int kn) {
        #pragma unroll
        for (int nt = 0; nt < 4; ++nt)
            BF[nt] = *(const f16x8*)&g_w2fragT[(size_t)((((wv * 4 + nt) * 16 + kn) * 64) + lane) * 8];
    };
    auto bloadR = [&](f16x8* BF, int kn) {
        #pragma unroll
        for (int nt = 0; nt < 4; ++nt)
            BF[nt] = *(const f16x8*)&g_w2fragR[(size_t)((((wv * 4 + nt) * 16 + kn) * 64) + lane) * 8];
    };

    f32x4 acc[2][4];
    #pragma unroll
    for (int a = 0; a < 2; ++a)
        #pragma unroll
        for (int c = 0; c < 4; ++c) acc[a][c] = (f32x4){0.f, 0.f, 0.f, 0.f};
    auto cluster = [&](const f16x8* AF, const f16x8* BF) {
        #pragma unroll
        for (int jt = 0; jt < 2; ++jt)
            #pragma unroll
            for (int nt = 0; nt < 4; ++nt)
                acc[jt][nt] = __builtin_amdgcn_mfma_f32_16x16x32_f16(AF[jt], BF[nt], acc[jt][nt], 0, 0, 0);
    };

    // ---- GEMM 1: A2 = H1 @ W2 ----
    {
        f16x8 aA[2], bA[4], aB[2], bB[4];
        aload(aA, 0); bloadT(bA, 0);
        #pragma unroll 1
        for (int ks = 0; ks < 16; ks += 2) {
            aload(aB, ks + 1); bloadT(bB, ks + 1);
            cluster(aA, bA);
            if (ks + 2 < 16) { aload(aA, ks + 2); bloadT(bA, ks + 2); }
            cluster(aB, bB);
        }
    }

    // ---- epilogue 1: h2 -> v2 (regs), c (global) ----
    float v2v[2][4][4];
    #pragma unroll
    for (int nt = 0; nt < 4; ++nt) {
        const int mcol = n0 + nt * 16 + l15;
        const float bb = b2[mcol], w3 = W3[mcol];
        #pragma unroll
        for (int jt = 0; jt < 2; ++jt) {
            #pragma unroll
            for (int r = 0; r < 4; ++r) {
                const int srow = jt * 16 + qd * 4 + r;
                const float h2 = tanhf(acc[jt][nt][r] + bb);
                const float t2 = 1.f - h2 * h2;
                const float v2 = w3 * t2;
                v2v[jt][nt][r] = v2;
                g_c[(size_t)(b0 + srow) * HID + mcol] = -2.f * h2 * v2;
            }
        }
    }
    __syncthreads();   // all h1 reads done

    // ---- re-stage alds with V2 ----
    #pragma unroll
    for (int nt = 0; nt < 4; ++nt) {
        const int mcol = n0 + nt * 16 + l15;
        #pragma unroll
        for (int jt = 0; jt < 2; ++jt) {
            #pragma unroll
            for (int r = 0; r < 4; ++r) {
                const int srow = jt * 16 + qd * 4 + r;
                alds[srow * HID + (((mcol >> 3) ^ (srow & 7)) << 3) + (mcol & 7)] = (f16)v2v[jt][nt][r];
            }
        }
    }
    __syncthreads();

    // ---- GEMM 2: U = V2 @ W2^T ----
    #pragma unroll
    for (int a = 0; a < 2; ++a)
        #pragma unroll
        for (int c = 0; c < 4; ++c) acc[a][c] = (f32x4){0.f, 0.f, 0.f, 0.f};
    {
        f16x8 aA[2], bA[4], aB[2], bB[4];
        aload(aA, 0); bloadR(bA, 0);
        #pragma unroll 1
        for (int ms = 0; ms < 16; ms += 2) {
            aload(aB, ms + 1); bloadR(bB, ms + 1);
            cluster(aA, bA);
            if (ms + 2 < 16) { aload(aA, ms + 2); bloadR(bA, ms + 2); }
            cluster(aB, bB);
        }
    }

    // ---- epilogue 2: s = (-2 h1 t1) * u ----
    #pragma unroll
    for (int nt = 0; nt < 4; ++nt) {
        const int kcol = n0 + nt * 16 + l15;
        #pragma unroll
        for (int jt = 0; jt < 2; ++jt) {
            #pragma unroll
            for (int r = 0; r < 4; ++r) {
                const int srow = jt * 16 + qd * 4 + r;
                const size_t idx = (size_t)(b0 + srow) * HID + kcol;
                g_s[idx] = g_n2h1t1[idx] * acc[jt][nt][r];
            }
        }
    }
}

// ---------------- main: 1 sample/block, lean regs -> 2 blocks/CU (4 waves/SIMD) ----------------
__global__ __launch_bounds__(NT, 4)   // cap 128 regs/wave: enables 2 co-resident blocks
void hnn_main(const float* __restrict__ W1, float* __restrict__ out) {
    __shared__ f16 awF[NQ * HID];          // 64KB: aw (=W1_x*t1), then F (=E*c)
    __shared__ float t1s[HID], cs[HID], ss[HID];   // 6KB
    __shared__ float red[8][NQ][2];                // 4KB -> total 75,776B: 2 blocks/CU

    const int tid = threadIdx.x, lane = tid & 63, wv = tid >> 6;
    const int l15 = lane & 15, qd = lane >> 4;
    const int b = blockIdx.x;

    t1s[tid] = g_t1[(size_t)b * HID + tid];
    cs[tid]  = g_c[(size_t)b * HID + tid];
    ss[tid]  = g_s[(size_t)b * HID + tid];

    // build aw[j][k] = W1[x_j,k] * t1[k] — coalesced 1KB bursts
    {
        const int col0 = lane * 8;
        const float4 ta = *(const float4*)&g_t1[(size_t)b * HID + col0];
        const float4 tb = *(const float4*)&g_t1[(size_t)b * HID + col0 + 4];
        f16x8* aw8 = (f16x8*)awF;
        #pragma unroll
        for (int jr = 0; jr < 8; ++jr) {
            const int j = wv * 8 + jr;
            const float4 wa = *(const float4*)&W1[(size_t)j * HID + col0];
            const float4 wb = *(const float4*)&W1[(size_t)j * HID + col0 + 4];
            f16x8 h;
            h[0] = (f16)(wa.x * ta.x); h[1] = (f16)(wa.y * ta.y);
            h[2] = (f16)(wa.z * ta.z); h[3] = (f16)(wa.w * ta.w);
            h[4] = (f16)(wb.x * tb.x); h[5] = (f16)(wb.y * tb.y);
            h[6] = (f16)(wb.z * tb.z); h[7] = (f16)(wb.w * tb.w);
            aw8[j * 64 + (lane ^ (j & 7))] = h;
        }
    }
    __syncthreads();

    const int n0 = wv * 64;
    f32x4 acc[4][4];   // 64 AGPR; E-phase: [mt][jt] (Et), R-phase: [jt][nt]
    #pragma unroll
    for (int a = 0; a < 4; ++a)
        #pragma unroll
        for (int c = 0; c < 4; ++c) acc[a][c] = (f32x4){0.f, 0.f, 0.f, 0.f};

    auto xload = [&](f16x8* XF, int kn) {
        const f16x8* a8 = (const f16x8*)awF;
        #pragma unroll
        for (int jt = 0; jt < 4; ++jt) {
            const int row = jt * 16 + l15;
            XF[jt] = a8[row * 64 + ((kn * 4 + qd) ^ (row & 7))];
        }
    };
    auto wloadT = [&](f16x8* WF, int kn) {
        #pragma unroll
        for (int nt = 0; nt < 4; ++nt)
            WF[nt] = *(const f16x8*)&g_w2fragT[(size_t)((((wv * 4 + nt) * 16 + kn) * 64) + lane) * 8];
    };
    auto wloadR = [&](f16x8* WF, int kn) {
        #pragma unroll
        for (int nt = 0; nt < 4; ++nt)
            WF[nt] = *(const f16x8*)&g_w2fragR[(size_t)((((wv * 4 + nt) * 16 + kn) * 64) + lane) * 8];
    };
    // Et cluster: Et[m][j] += W2t-frag[m] * aw-frag[j]
    auto clusterE = [&](const f16x8* WF, const f16x8* XF) {
        #pragma unroll
        for (int mt = 0; mt < 4; ++mt)
            #pragma unroll
            for (int jt = 0; jt < 4; ++jt)
                acc[mt][jt] = __builtin_amdgcn_mfma_f32_16x16x32_f16(WF[mt], XF[jt], acc[mt][jt], 0, 0, 0);
    };
    // R cluster: R[j][k] += F-frag[j] * W2R-frag[k]
    auto clusterR = [&](const f16x8* XF, const f16x8* WF) {
        #pragma unroll
        for (int jt = 0; jt < 4; ++jt)
            #pragma unroll
            for (int nt = 0; nt < 4; ++nt)
                acc[jt][nt] = __builtin_amdgcn_mfma_f32_16x16x32_f16(XF[jt], WF[nt], acc[jt][nt], 0, 0, 0);
    };

    // ---- E GEMM (transposed): single-A-buffer + double-B pipeline ----
    {
        f16x8 xP[4], wA[4], wB[4];
        xload(xP, 0); wloadT(wA, 0);
        #pragma unroll 1
        for (int ks = 0; ks < 16; ks += 2) {
            wloadT(wB, ks + 1);
            clusterE(wA, xP);
            xload(xP, ks + 1);
            if (ks + 2 < 16) wloadT(wA, ks + 2);
            clusterE(wB, xP);
            if (ks + 2 < 16) xload(xP, ks + 2);
        }
    }
    __syncthreads();

    // ---- F[j][m] = Et[m][j] * c[m], vectorized f16x4 writes ----
    #pragma unroll
    for (int mt = 0; mt < 4; ++mt) {
        const int mbase = n0 + mt * 16 + qd * 4;
        const float4 cv = *(const float4*)&cs[mbase];
        const int chunk = mbase >> 3;
        const int half4 = (mbase >> 2) & 1;
        #pragma unroll
        for (int jt = 0; jt < 4; ++jt) {
            const int j = jt * 16 + l15;
            f16x4 h;
            h[0] = (f16)(acc[mt][jt][0] * cv.x);
            h[1] = (f16)(acc[mt][jt][1] * cv.y);
            h[2] = (f16)(acc[mt][jt][2] * cv.z);
            h[3] = (f16)(acc[mt][jt][3] * cv.w);
            *(f16x4*)&awF[j * HID + ((chunk ^ (j & 7)) << 3) + half4 * 4] = h;
        }
    }
    __syncthreads();

    // ---- R GEMM: R[j][k] = F @ W2^T ----
    #pragma unroll
    for (int a = 0; a < 4; ++a)
        #pragma unroll
        for (int c = 0; c < 4; ++c) acc[a][c] = (f32x4){0.f, 0.f, 0.f, 0.f};
    {
        f16x8 xP[4], wA[4], wB[4];
        xload(xP, 0); wloadR(wA, 0);
        #pragma unroll 1
        for (int ms = 0; ms < 16; ms += 2) {
            wloadR(wB, ms + 1);
            clusterR(xP, wA);
            xload(xP, ms + 1);
            if (ms + 2 < 16) wloadR(wA, ms + 2);
            clusterR(xP, wB);
            if (ms + 2 < 16) xload(xP, ms + 2);
        }
    }

    // ---- fold: base = R*t1 + s*W1x ; vq/vp row-dots, 16-lane reduce ----
    float t1k[4], sk[4];
    #pragma unroll
    for (int nt = 0; nt < 4; ++nt) {
        const int k = n0 + nt * 16 + l15;
        t1k[nt] = t1s[k];
        sk[nt]  = ss[k];
    }
    #pragma unroll
    for (int jt = 0; jt < 4; ++jt) {
        #pragma unroll
        for (int r = 0; r < 4; ++r) {
            const int j = jt * 16 + qd * 4 + r;
            float vq = 0.f, vp = 0.f;
            #pragma unroll
            for (int nt = 0; nt < 4; ++nt) {
                const int k = n0 + nt * 16 + l15;
                const float w1x = W1[(size_t)j * HID + k];
                const float w1q = W1[(size_t)(NQ + j) * HID + k];
                const float w1p = W1[(size_t)(2 * NQ + j) * HID + k];
                const float base = acc[jt][nt][r] * t1k[nt] + sk[nt] * w1x;
                vq += w1q * base;
                vp += w1p * base;
            }
            vq += __shfl_xor(vq, 1, 64); vq += __shfl_xor(vq, 2, 64);
            vq += __shfl_xor(vq, 4, 64); vq += __shfl_xor(vq, 8, 64);
            vp += __shfl_xor(vp, 1, 64); vp += __shfl_xor(vp, 2, 64);
            vp += __shfl_xor(vp, 4, 64); vp += __shfl_xor(vp, 8, 64);
            if (l15 == 0) {
                red[wv][j][0] = vq;
                red[wv][j][1] = vp;
            }
        }
    }
    __syncthreads();

    if (tid < NQ * 2) {
        const int j = tid >> 1, c = tid & 1;
        float v = 0.f;
        #pragma unroll
        for (int w = 0; w < 8; ++w) v += red[w][j][c];
        if (c == 0) out[(size_t)BATCH * NQ + (size_t)b * NQ + j] = -v;  // p_dot = -dH_dq_dx
        else        out[(size_t)b * NQ + j] = -v;                      // q_dot = -dH_dp_dx
    }
}

extern "C" void kernel_launch(void* const* d_in, const int* in_sizes, int n_in,
                              void* d_out, int out_size, void* d_ws, size_t ws_size,
                              hipStream_t stream) {
    const float* x  = (const float*)d_in[0];
    const float* q  = (const float*)d_in[1];
    const float* p  = (const float*)d_in[2];
    const float* W1 = (const float*)d_in[3];
    const float* b1 = (const float*)d_in[4];
    const float* W2 = (const float*)d_in[5];
    const float* b2 = (const float*)d_in[6];
    const float* W3 = (const float*)d_in[7];
    float* out = (float*)d_out;

    prep_frag<<<HID, HID, 0, stream>>>(W2);
    fwd1<<<BATCH / SPB1, NT, 0, stream>>>(x, q, p, W1, b1);
    fwd23<<<BATCH / SPB2, NT, 0, stream>>>(b2, W3);
    hnn_main<<<BATCH, NT, 0, stream>>>(W1, out);
}

// Round 12
// 627.692 us; speedup vs baseline: 1.2451x; 1.2451x over previous
//
#include <hip/hip_runtime.h>

#define BATCH 8192
#define NQ 64          // spatial dim n
#define HID 512
#define DIN 192        // 3*n
#define NT 512         // threads per block (8 waves)
#define SPB1 16        // samples per block, fwd1
#define SPB2 32        // samples per block, fwd23/fwd4
#define SPB 2          // samples per block, main

typedef _Float16 f16;
typedef _Float16 f16x8 __attribute__((ext_vector_type(8)));
typedef _Float16 f16x4 __attribute__((ext_vector_type(4)));
typedef float f32x4 __attribute__((ext_vector_type(4)));

// W2 in MFMA-fragment-major order (pre-swizzled global, coalesced 1KB frag loads)
__device__ f16 g_w2fragT[HID * HID];  // frag for contraction k
__device__ f16 g_w2fragR[HID * HID];  // frag for contraction m
__device__ f16 g_Gfrag[128 * HID];    // B-frag for term2: G[j,k]=W1q/p[j,k]*W1x[j,k]
// per-sample forward intermediates
__device__ f16   g_h1[(size_t)BATCH * HID];
__device__ float g_t1[(size_t)BATCH * HID];
__device__ float g_n2h1t1[(size_t)BATCH * HID];
__device__ float g_c[(size_t)BATCH * HID];
__device__ float g_s[(size_t)BATCH * HID];
__device__ float g_t2[(size_t)BATCH * 128];   // term2: cols 0-63 = q, 64-127 = p

// ---------------- prep: fragment-major f16 W2 layouts ----------------
__global__ void prep_frag(const float* __restrict__ W2) {
    const int k = blockIdx.x;    // 512
    const int m = threadIdx.x;   // 512
    const f16 v = (f16)W2[k * HID + m];
    g_w2fragT[(size_t)((((m >> 4) * 16 + (k >> 5)) * 64) + ((m & 15) | (((k >> 3) & 3) << 4))) * 8 + (k & 7)] = v;
    g_w2fragR[(size_t)((((k >> 4) * 16 + (m >> 5)) * 64) + ((k & 15) | (((m >> 3) & 3) << 4))) * 8 + (m & 7)] = v;
}

// ---------------- prep: G fragments (term2 weights, sample-independent) ----------------
__global__ void prep_g(const float* __restrict__ W1) {
    const int j = blockIdx.x;    // 128
    const int k = threadIdx.x;   // 512
    const int jj = j & 63;
    const float w = (j < 64)
        ? W1[(64 + jj) * HID + k] * W1[jj * HID + k]     // G_q
        : W1[(128 + jj) * HID + k] * W1[jj * HID + k];   // G_p
    g_Gfrag[(size_t)((((j >> 4) * 16 + (k >> 5)) * 64) + ((j & 15) | (((k >> 3) & 3) << 4))) * 8 + (k & 7)] = (f16)w;
}

// ---------------- fwd1: layer1 in fp32, batched over samples ----------------
__global__ __launch_bounds__(NT)
void fwd1(const float* __restrict__ x, const float* __restrict__ q,
          const float* __restrict__ p, const float* __restrict__ W1,
          const float* __restrict__ b1) {
    __shared__ float zs[SPB1][DIN];
    const int b0 = blockIdx.x * SPB1;
    const int tid = threadIdx.x;
    for (int i = tid; i < SPB1 * DIN; i += NT) {
        const int s = i / DIN, kk = i % DIN;
        float v;
        if (kk < NQ)          v = x[(b0 + s) * NQ + kk];
        else if (kk < 2 * NQ) v = q[(b0 + s) * NQ + kk - NQ];
        else                  v = p[(b0 + s) * NQ + kk - 2 * NQ];
        zs[s][kk] = v;
    }
    __syncthreads();
    const int m = tid;
    float acc[SPB1];
    #pragma unroll
    for (int s = 0; s < SPB1; ++s) acc[s] = 0.f;
    #pragma unroll 2
    for (int k = 0; k < DIN; ++k) {
        const float w = W1[k * HID + m];
        #pragma unroll
        for (int s = 0; s < SPB1; ++s) acc[s] += zs[s][k] * w;
    }
    const float bb = b1[m];
    #pragma unroll
    for (int s = 0; s < SPB1; ++s) {
        const float h1 = tanhf(acc[s] + bb);
        const float t1 = 1.f - h1 * h1;
        const size_t idx = (size_t)(b0 + s) * HID + m;
        g_h1[idx] = (f16)h1;
        g_t1[idx] = t1;
        g_n2h1t1[idx] = -2.f * h1 * t1;
    }
}

// ---------------- fwd23: H2/v2/c then U = V2@W2^T, s — fused ----------------
__global__ __launch_bounds__(NT)
void fwd23(const float* __restrict__ b2, const float* __restrict__ W3) {
    __shared__ f16 alds[SPB2 * HID];
    const int b0 = blockIdx.x * SPB2;
    const int tid = threadIdx.x, lane = tid & 63, wv = tid >> 6;
    const int l15 = lane & 15, qd = lane >> 4;
    const int n0 = wv * 64;

    {
        const int s = tid >> 4;
        f16x8* a8 = (f16x8*)alds;
        #pragma unroll
        for (int c = 0; c < 4; ++c) {
            const int kc = (tid & 15) + c * 16;
            const f16x8 v = *(const f16x8*)&g_h1[(size_t)(b0 + s) * HID + kc * 8];
            a8[s * 64 + (kc ^ (s & 7))] = v;
        }
    }
    __syncthreads();

    const f16x8* a8 = (const f16x8*)alds;
    auto aload = [&](f16x8* AF, int kn) {
        #pragma unroll
        for (int jt = 0; jt < 2; ++jt) {
            const int row = jt * 16 + l15;
            AF[jt] = a8[row * 64 + ((kn * 4 + qd) ^ (row & 7))];
        }
    };
    auto bloadT = [&](f16x8* BF, int kn) {
        #pragma unroll
        for (int nt = 0; nt < 4; ++nt)
            BF[nt] = *(const f16x8*)&g_w2fragT[(size_t)((((wv * 4 + nt) * 16 + kn) * 64) + lane) * 8];
    };
    auto bloadR = [&](f16x8* BF, int kn) {
        #pragma unroll
        for (int nt = 0; nt < 4; ++nt)
            BF[nt] = *(const f16x8*)&g_w2fragR[(size_t)((((wv * 4 + nt) * 16 + kn) * 64) + lane) * 8];
    };

    f32x4 acc[2][4];
    #pragma unroll
    for (int a = 0; a < 2; ++a)
        #pragma unroll
        for (int c = 0; c < 4; ++c) acc[a][c] = (f32x4){0.f, 0.f, 0.f, 0.f};
    auto cluster = [&](const f16x8* AF, const f16x8* BF) {
        #pragma unroll
        for (int jt = 0; jt < 2; ++jt)
            #pragma unroll
            for (int nt = 0; nt < 4; ++nt)
                acc[jt][nt] = __builtin_amdgcn_mfma_f32_16x16x32_f16(AF[jt], BF[nt], acc[jt][nt], 0, 0, 0);
    };

    // ---- GEMM 1: A2 = H1 @ W2 ----
    {
        f16x8 aA[2], bA[4], aB[2], bB[4];
        aload(aA, 0); bloadT(bA, 0);
        #pragma unroll 1
        for (int ks = 0; ks < 16; ks += 2) {
            aload(aB, ks + 1); bloadT(bB, ks + 1);
            cluster(aA, bA);
            if (ks + 2 < 16) { aload(aA, ks + 2); bloadT(bA, ks + 2); }
            cluster(aB, bB);
        }
    }

    // ---- epilogue 1: h2 -> v2 (regs), c (global) ----
    float v2v[2][4][4];
    #pragma unroll
    for (int nt = 0; nt < 4; ++nt) {
        const int mcol = n0 + nt * 16 + l15;
        const float bb = b2[mcol], w3 = W3[mcol];
        #pragma unroll
        for (int jt = 0; jt < 2; ++jt) {
            #pragma unroll
            for (int r = 0; r < 4; ++r) {
                const int srow = jt * 16 + qd * 4 + r;
                const float h2 = tanhf(acc[jt][nt][r] + bb);
                const float t2 = 1.f - h2 * h2;
                const float v2 = w3 * t2;
                v2v[jt][nt][r] = v2;
                g_c[(size_t)(b0 + srow) * HID + mcol] = -2.f * h2 * v2;
            }
        }
    }
    __syncthreads();   // all h1 reads done

    // ---- re-stage alds with V2 ----
    #pragma unroll
    for (int nt = 0; nt < 4; ++nt) {
        const int mcol = n0 + nt * 16 + l15;
        #pragma unroll
        for (int jt = 0; jt < 2; ++jt) {
            #pragma unroll
            for (int r = 0; r < 4; ++r) {
                const int srow = jt * 16 + qd * 4 + r;
                alds[srow * HID + (((mcol >> 3) ^ (srow & 7)) << 3) + (mcol & 7)] = (f16)v2v[jt][nt][r];
            }
        }
    }
    __syncthreads();

    // ---- GEMM 2: U = V2 @ W2^T ----
    #pragma unroll
    for (int a = 0; a < 2; ++a)
        #pragma unroll
        for (int c = 0; c < 4; ++c) acc[a][c] = (f32x4){0.f, 0.f, 0.f, 0.f};
    {
        f16x8 aA[2], bA[4], aB[2], bB[4];
        aload(aA, 0); bloadR(bA, 0);
        #pragma unroll 1
        for (int ms = 0; ms < 16; ms += 2) {
            aload(aB, ms + 1); bloadR(bB, ms + 1);
            cluster(aA, bA);
            if (ms + 2 < 16) { aload(aA, ms + 2); bloadR(bA, ms + 2); }
            cluster(aB, bB);
        }
    }

    // ---- epilogue 2: s = (-2 h1 t1) * u ----
    #pragma unroll
    for (int nt = 0; nt < 4; ++nt) {
        const int kcol = n0 + nt * 16 + l15;
        #pragma unroll
        for (int jt = 0; jt < 2; ++jt) {
            #pragma unroll
            for (int r = 0; r < 4; ++r) {
                const int srow = jt * 16 + qd * 4 + r;
                const size_t idx = (size_t)(b0 + srow) * HID + kcol;
                g_s[idx] = g_n2h1t1[idx] * acc[jt][nt][r];
            }
        }
    }
}

// ---------------- fwd4: term2 = s @ G^T  ([32-sample tile] -> [128 j]) ----------------
__global__ __launch_bounds__(NT)
void fwd4() {
    __shared__ f16 alds[SPB2 * HID];
    const int b0 = blockIdx.x * SPB2;
    const int tid = threadIdx.x, lane = tid & 63, wv = tid >> 6;
    const int l15 = lane & 15, qd = lane >> 4;
    {
        const int sr = tid >> 4;
        f16x8* a8 = (f16x8*)alds;
        #pragma unroll
        for (int c = 0; c < 4; ++c) {
            const int kc = (tid & 15) + c * 16;
            const float* sp = &g_s[(size_t)(b0 + sr) * HID + kc * 8];
            f16x8 h;
            #pragma unroll
            for (int e = 0; e < 8; ++e) h[e] = (f16)sp[e];
            a8[sr * 64 + (kc ^ (sr & 7))] = h;
        }
    }
    __syncthreads();
    f32x4 acc[2];
    acc[0] = (f32x4){0.f, 0.f, 0.f, 0.f};
    acc[1] = (f32x4){0.f, 0.f, 0.f, 0.f};
    const f16x8* a8 = (const f16x8*)alds;
    #pragma unroll 2
    for (int ks = 0; ks < 16; ++ks) {
        f16x8 afr[2], bfr;
        #pragma unroll
        for (int jt = 0; jt < 2; ++jt) {
            const int row = jt * 16 + l15;
            afr[jt] = a8[row * 64 + ((ks * 4 + qd) ^ (row & 7))];
        }
        bfr = *(const f16x8*)&g_Gfrag[(size_t)(((wv * 16 + ks) * 64) + lane) * 8];
        #pragma unroll
        for (int jt = 0; jt < 2; ++jt)
            acc[jt] = __builtin_amdgcn_mfma_f32_16x16x32_f16(afr[jt], bfr, acc[jt], 0, 0, 0);
    }
    const int jc = wv * 16 + l15;
    #pragma unroll
    for (int jt = 0; jt < 2; ++jt)
        #pragma unroll
        for (int r = 0; r < 4; ++r) {
            const int srow = jt * 16 + qd * 4 + r;
            g_t2[(size_t)(b0 + srow) * 128 + jc] = acc[jt][r];
        }
}

// ---------------- main: 2 samples/block, Et-GEMM -> vectorized F -> R-GEMM -> slim fold ----------------
__global__ __launch_bounds__(NT, 2)   // cap 256 regs total (VGPR+AGPR): no spill
void hnn_main(const float* __restrict__ W1, float* __restrict__ out) {
    __shared__ f16 awF[SPB][NQ * HID];       // 128KB: aw (=W1_x*t1), then F (=E*c)
    __shared__ float t1s[SPB][HID], cs[SPB][HID];
    __shared__ float red[SPB][8][NQ][2];     // per-wave partials (no atomics)

    const int tid = threadIdx.x, lane = tid & 63, wv = tid >> 6;
    const int l15 = lane & 15, qd = lane >> 4;
    const int b0 = blockIdx.x * SPB;

    #pragma unroll
    for (int s = 0; s < SPB; ++s) {
        t1s[s][tid] = g_t1[(size_t)(b0 + s) * HID + tid];
        cs[s][tid]  = g_c[(size_t)(b0 + s) * HID + tid];
    }

    // build aw[s][j][k] = W1[x_j,k] * t1[s][k] — coalesced; W1 row read once for both samples
    {
        const int col0 = lane * 8;
        const float4 ta0 = *(const float4*)&g_t1[(size_t)(b0 + 0) * HID + col0];
        const float4 tb0 = *(const float4*)&g_t1[(size_t)(b0 + 0) * HID + col0 + 4];
        const float4 ta1 = *(const float4*)&g_t1[(size_t)(b0 + 1) * HID + col0];
        const float4 tb1 = *(const float4*)&g_t1[(size_t)(b0 + 1) * HID + col0 + 4];
        f16x8* aw80 = (f16x8*)awF[0];
        f16x8* aw81 = (f16x8*)awF[1];
        #pragma unroll
        for (int jr = 0; jr < 8; ++jr) {
            const int j = wv * 8 + jr;
            const float4 wa = *(const float4*)&W1[(size_t)j * HID + col0];
            const float4 wb = *(const float4*)&W1[(size_t)j * HID + col0 + 4];
            f16x8 h0, h1v;
            h0[0] = (f16)(wa.x * ta0.x); h0[1] = (f16)(wa.y * ta0.y);
            h0[2] = (f16)(wa.z * ta0.z); h0[3] = (f16)(wa.w * ta0.w);
            h0[4] = (f16)(wb.x * tb0.x); h0[5] = (f16)(wb.y * tb0.y);
            h0[6] = (f16)(wb.z * tb0.z); h0[7] = (f16)(wb.w * tb0.w);
            h1v[0] = (f16)(wa.x * ta1.x); h1v[1] = (f16)(wa.y * ta1.y);
            h1v[2] = (f16)(wa.z * ta1.z); h1v[3] = (f16)(wa.w * ta1.w);
            h1v[4] = (f16)(wb.x * tb1.x); h1v[5] = (f16)(wb.y * tb1.y);
            h1v[6] = (f16)(wb.z * tb1.z); h1v[7] = (f16)(wb.w * tb1.w);
            aw80[j * 64 + (lane ^ (j & 7))] = h0;
            aw81[j * 64 + (lane ^ (j & 7))] = h1v;
        }
    }
    __syncthreads();

    const int n0 = wv * 64;
    f32x4 acc4[SPB][4][4];
    #pragma unroll
    for (int s = 0; s < SPB; ++s)
        #pragma unroll
        for (int a = 0; a < 4; ++a)
            #pragma unroll
            for (int c = 0; c < 4; ++c) acc4[s][a][c] = (f32x4){0.f, 0.f, 0.f, 0.f};

    auto xloadS = [&](f16x8* XF, int kn, int s) {
        const f16x8* a8 = (const f16x8*)awF[s];
        #pragma unroll
        for (int jt = 0; jt < 4; ++jt) {
            const int row = jt * 16 + l15;
            XF[jt] = a8[row * 64 + ((kn * 4 + qd) ^ (row & 7))];
        }
    };
    auto wloadT = [&](f16x8* WF, int kn) {
        #pragma unroll
        for (int nt = 0; nt < 4; ++nt)
            WF[nt] = *(const f16x8*)&g_w2fragT[(size_t)((((wv * 4 + nt) * 16 + kn) * 64) + lane) * 8];
    };
    auto wloadR = [&](f16x8* WF, int kn) {
        #pragma unroll
        for (int nt = 0; nt < 4; ++nt)
            WF[nt] = *(const f16x8*)&g_w2fragR[(size_t)((((wv * 4 + nt) * 16 + kn) * 64) + lane) * 8];
    };
    auto clusterE = [&](const f16x8* WF, const f16x8* XF, int s) {
        #pragma unroll
        for (int mt = 0; mt < 4; ++mt)
            #pragma unroll
            for (int jt = 0; jt < 4; ++jt)
                acc4[s][mt][jt] = __builtin_amdgcn_mfma_f32_16x16x32_f16(WF[mt], XF[jt], acc4[s][mt][jt], 0, 0, 0);
    };
    auto clusterR = [&](const f16x8* XF, const f16x8* WF, int s) {
        #pragma unroll
        for (int jt = 0; jt < 4; ++jt)
            #pragma unroll
            for (int nt = 0; nt < 4; ++nt)
                acc4[s][jt][nt] = __builtin_amdgcn_mfma_f32_16x16x32_f16(XF[jt], WF[nt], acc4[s][jt][nt], 0, 0, 0);
    };

    // ---- E GEMM (transposed): Et[s][m][j] ----
    {
        f16x8 xP[4], xQ[4], wA[4], wB[4];
        xloadS(xP, 0, 0); wloadT(wA, 0);
        #pragma unroll 1
        for (int ks = 0; ks < 16; ks += 2) {
            xloadS(xQ, ks, 1);
            wloadT(wB, ks + 1);
            clusterE(wA, xP, 0);
            xloadS(xP, ks + 1, 0);
            clusterE(wA, xQ, 1);
            xloadS(xQ, ks + 1, 1);
            if (ks + 2 < 16) wloadT(wA, ks + 2);
            clusterE(wB, xP, 0);
            if (ks + 2 < 16) xloadS(xP, ks + 2, 0);
            clusterE(wB, xQ, 1);
        }
    }
    __syncthreads();

    // ---- F[j][m] = Et[m][j] * c[m], vectorized f16x4 writes ----
    #pragma unroll
    for (int s = 0; s < SPB; ++s) {
        #pragma unroll
        for (int mt = 0; mt < 4; ++mt) {
            const int mbase = n0 + mt * 16 + qd * 4;
            const float4 cv = *(const float4*)&cs[s][mbase];
            const int chunk = mbase >> 3;
            const int half4 = (mbase >> 2) & 1;
            #pragma unroll
            for (int jt = 0; jt < 4; ++jt) {
                const int j = jt * 16 + l15;
                f16x4 h;
                h[0] = (f16)(acc4[s][mt][jt][0] * cv.x);
                h[1] = (f16)(acc4[s][mt][jt][1] * cv.y);
                h[2] = (f16)(acc4[s][mt][jt][2] * cv.z);
                h[3] = (f16)(acc4[s][mt][jt][3] * cv.w);
                *(f16x4*)&awF[s][j * HID + ((chunk ^ (j & 7)) << 3) + half4 * 4] = h;
            }
        }
    }
    __syncthreads();

    // ---- R GEMM: R[s][64 j][512 k] = F @ W2^T ----
    #pragma unroll
    for (int s = 0; s < SPB; ++s)
        #pragma unroll
        for (int a = 0; a < 4; ++a)
            #pragma unroll
            for (int c = 0; c < 4; ++c) acc4[s][a][c] = (f32x4){0.f, 0.f, 0.f, 0.f};
    {
        f16x8 xP[4], xQ[4], wA[4], wB[4];
        xloadS(xP, 0, 0); wloadR(wA, 0);
        #pragma unroll 1
        for (int ms = 0; ms < 16; ms += 2) {
            xloadS(xQ, ms, 1);
            wloadR(wB, ms + 1);
            clusterR(xP, wA, 0);
            xloadS(xP, ms + 1, 0);
            clusterR(xQ, wA, 1);
            xloadS(xQ, ms + 1, 1);
            if (ms + 2 < 16) wloadR(wA, ms + 2);
            clusterR(xP, wB, 0);
            if (ms + 2 < 16) xloadS(xP, ms + 2, 0);
            clusterR(xQ, wB, 1);
        }
    }

    // ---- slim fold: base = R*t1 only (s-term handled by fwd4/g_t2) ----
    float t1k[SPB][4];
    #pragma unroll
    for (int s = 0; s < SPB; ++s)
        #pragma unroll
        for (int nt = 0; nt < 4; ++nt)
            t1k[s][nt] = t1s[s][n0 + nt * 16 + l15];
    #pragma unroll
    for (int jt = 0; jt < 4; ++jt) {
        #pragma unroll
        for (int r = 0; r < 4; ++r) {
            const int j = jt * 16 + qd * 4 + r;
            float vq0 = 0.f, vp0 = 0.f, vq1 = 0.f, vp1 = 0.f;
            #pragma unroll
            for (int nt = 0; nt < 4; ++nt) {
                const int k = n0 + nt * 16 + l15;
                const float w1q = W1[(size_t)(NQ + j) * HID + k];
                const float w1p = W1[(size_t)(2 * NQ + j) * HID + k];
                const float base0 = acc4[0][jt][nt][r] * t1k[0][nt];
                const float base1 = acc4[1][jt][nt][r] * t1k[1][nt];
                vq0 += w1q * base0; vp0 += w1p * base0;
                vq1 += w1q * base1; vp1 += w1p * base1;
            }
            vq0 += __shfl_xor(vq0, 1, 64); vq0 += __shfl_xor(vq0, 2, 64);
            vq0 += __shfl_xor(vq0, 4, 64); vq0 += __shfl_xor(vq0, 8, 64);
            vp0 += __shfl_xor(vp0, 1, 64); vp0 += __shfl_xor(vp0, 2, 64);
            vp0 += __shfl_xor(vp0, 4, 64); vp0 += __shfl_xor(vp0, 8, 64);
            vq1 += __shfl_xor(vq1, 1, 64); vq1 += __shfl_xor(vq1, 2, 64);
            vq1 += __shfl_xor(vq1, 4, 64); vq1 += __shfl_xor(vq1, 8, 64);
            vp1 += __shfl_xor(vp1, 1, 64); vp1 += __shfl_xor(vp1, 2, 64);
            vp1 += __shfl_xor(vp1, 4, 64); vp1 += __shfl_xor(vp1, 8, 64);
            if (l15 == 0) {
                red[0][wv][j][0] = vq0;
                red[0][wv][j][1] = vp0;
                red[1][wv][j][0] = vq1;
                red[1][wv][j][1] = vp1;
            }
        }
    }
    __syncthreads();

    if (tid < SPB * NQ * 2) {
        const int s = tid >> 7, j = (tid >> 1) & 63, c = tid & 1;
        float v = 0.f;
        #pragma unroll
        for (int w = 0; w < 8; ++w) v += red[s][w][j][c];
        v += g_t2[(size_t)(b0 + s) * 128 + c * 64 + j];
        if (c == 0) out[(size_t)BATCH * NQ + (size_t)(b0 + s) * NQ + j] = -v;  // p_dot = -dH_dq_dx
        else        out[(size_t)(b0 + s) * NQ + j] = -v;                       // q_dot = -dH_dp_dx
    }
}

extern "C" void kernel_launch(void* const* d_in, const int* in_sizes, int n_in,
                              void* d_out, int out_size, void* d_ws, size_t ws_size,
                              hipStream_t stream) {
    const float* x  = (const float*)d_in[0];
    const float* q  = (const float*)d_in[1];
    const float* p  = (const float*)d_in[2];
    const float* W1 = (const float*)d_in[3];
    const float* b1 = (const float*)d_in[4];
    const float* W2 = (const float*)d_in[5];
    const float* b2 = (const float*)d_in[6];
    const float* W3 = (const float*)d_in[7];
    float* out = (float*)d_out;

    prep_frag<<<HID, HID, 0, stream>>>(W2);
    prep_g<<<128, HID, 0, stream>>>(W1);
    fwd1<<<BATCH / SPB1, NT, 0, stream>>>(x, q, p, W1, b1);
    fwd23<<<BATCH / SPB2, NT, 0, stream>>>(b2, W3);
    fwd4<<<BATCH / SPB2, NT, 0, stream>>>();
    hnn_main<<<BATCH / SPB, NT, 0, stream>>>(W1, out);
}

// Round 13
// 595.988 us; speedup vs baseline: 1.3113x; 1.0532x over previous
//
#include <hip/hip_runtime.h>

#define BATCH 8192
#define NQ 64          // spatial dim n
#define HID 512
#define DIN 192        // 3*n
#define NT 512         // threads per block (8 waves)
#define SPB1 16        // samples per block, fwd1
#define SPB2 32        // samples per block, fwd23/fwd4
#define SPB 2          // samples per block, main

typedef _Float16 f16;
typedef _Float16 f16x8 __attribute__((ext_vector_type(8)));
typedef _Float16 f16x4 __attribute__((ext_vector_type(4)));
typedef float f32x4 __attribute__((ext_vector_type(4)));

// W2 in MFMA-fragment-major order (pre-swizzled global, coalesced 1KB frag loads)
__device__ f16 g_w2fragT[HID * HID];  // frag for contraction k
__device__ f16 g_w2fragR[HID * HID];  // frag for contraction m
__device__ f16 g_Gfrag[128 * HID];    // B-frag for term2: G[j,k]=W1q/p[j,k]*W1x[j,k]
// per-sample forward intermediates
__device__ f16   g_h1[(size_t)BATCH * HID];
__device__ float g_t1[(size_t)BATCH * HID];
__device__ float g_n2h1t1[(size_t)BATCH * HID];
__device__ float g_c[(size_t)BATCH * HID];
__device__ float g_s[(size_t)BATCH * HID];
__device__ float g_t2[(size_t)BATCH * 128];   // term2: cols 0-63 = q, 64-127 = p

// ---------------- prep: fragment-major f16 W2 layouts ----------------
__global__ void prep_frag(const float* __restrict__ W2) {
    const int k = blockIdx.x;    // 512
    const int m = threadIdx.x;   // 512
    const f16 v = (f16)W2[k * HID + m];
    g_w2fragT[(size_t)((((m >> 4) * 16 + (k >> 5)) * 64) + ((m & 15) | (((k >> 3) & 3) << 4))) * 8 + (k & 7)] = v;
    g_w2fragR[(size_t)((((k >> 4) * 16 + (m >> 5)) * 64) + ((k & 15) | (((m >> 3) & 3) << 4))) * 8 + (m & 7)] = v;
}

// ---------------- prep: G fragments (term2 weights, sample-independent) ----------------
__global__ void prep_g(const float* __restrict__ W1) {
    const int j = blockIdx.x;    // 128
    const int k = threadIdx.x;   // 512
    const int jj = j & 63;
    const float w = (j < 64)
        ? W1[(64 + jj) * HID + k] * W1[jj * HID + k]     // G_q
        : W1[(128 + jj) * HID + k] * W1[jj * HID + k];   // G_p
    g_Gfrag[(size_t)((((j >> 4) * 16 + (k >> 5)) * 64) + ((j & 15) | (((k >> 3) & 3) << 4))) * 8 + (k & 7)] = (f16)w;
}

// ---------------- fwd1: layer1 in fp32, batched over samples ----------------
__global__ __launch_bounds__(NT)
void fwd1(const float* __restrict__ x, const float* __restrict__ q,
          const float* __restrict__ p, const float* __restrict__ W1,
          const float* __restrict__ b1) {
    __shared__ float zs[SPB1][DIN];
    const int b0 = blockIdx.x * SPB1;
    const int tid = threadIdx.x;
    for (int i = tid; i < SPB1 * DIN; i += NT) {
        const int s = i / DIN, kk = i % DIN;
        float v;
        if (kk < NQ)          v = x[(b0 + s) * NQ + kk];
        else if (kk < 2 * NQ) v = q[(b0 + s) * NQ + kk - NQ];
        else                  v = p[(b0 + s) * NQ + kk - 2 * NQ];
        zs[s][kk] = v;
    }
    __syncthreads();
    const int m = tid;
    float acc[SPB1];
    #pragma unroll
    for (int s = 0; s < SPB1; ++s) acc[s] = 0.f;
    #pragma unroll 2
    for (int k = 0; k < DIN; ++k) {
        const float w = W1[k * HID + m];
        #pragma unroll
        for (int s = 0; s < SPB1; ++s) acc[s] += zs[s][k] * w;
    }
    const float bb = b1[m];
    #pragma unroll
    for (int s = 0; s < SPB1; ++s) {
        const float h1 = tanhf(acc[s] + bb);
        const float t1 = 1.f - h1 * h1;
        const size_t idx = (size_t)(b0 + s) * HID + m;
        g_h1[idx] = (f16)h1;
        g_t1[idx] = t1;
        g_n2h1t1[idx] = -2.f * h1 * t1;
    }
}

// ---------------- fwd23: H2/v2/c then U = V2@W2^T, s — fused ----------------
__global__ __launch_bounds__(NT)
void fwd23(const float* __restrict__ b2, const float* __restrict__ W3) {
    __shared__ f16 alds[SPB2 * HID];
    const int b0 = blockIdx.x * SPB2;
    const int tid = threadIdx.x, lane = tid & 63, wv = tid >> 6;
    const int l15 = lane & 15, qd = lane >> 4;
    const int n0 = wv * 64;

    {
        const int s = tid >> 4;
        f16x8* a8 = (f16x8*)alds;
        #pragma unroll
        for (int c = 0; c < 4; ++c) {
            const int kc = (tid & 15) + c * 16;
            const f16x8 v = *(const f16x8*)&g_h1[(size_t)(b0 + s) * HID + kc * 8];
            a8[s * 64 + (kc ^ (s & 7))] = v;
        }
    }
    __syncthreads();

    const f16x8* a8 = (const f16x8*)alds;
    auto aload = [&](f16x8* AF, int kn) {
        #pragma unroll
        for (int jt = 0; jt < 2; ++jt) {
            const int row = jt * 16 + l15;
            AF[jt] = a8[row * 64 + ((kn * 4 + qd) ^ (row & 7))];
        }
    };
    auto bloadT = [&](f16x8* BF, int kn) {
        #pragma unroll
        for (int nt = 0; nt < 4; ++nt)
            BF[nt] = *(const f16x8*)&g_w2fragT[(size_t)((((wv * 4 + nt) * 16 + kn) * 64) + lane) * 8];
    };
    auto bloadR = [&](f16x8* BF, int kn) {
        #pragma unroll
        for (int nt = 0; nt < 4; ++nt)
            BF[nt] = *(const f16x8*)&g_w2fragR[(size_t)((((wv * 4 + nt) * 16 + kn) * 64) + lane) * 8];
    };

    f32x4 acc[2][4];
    #pragma unroll
    for (int a = 0; a < 2; ++a)
        #pragma unroll
        for (int c = 0; c < 4; ++c) acc[a][c] = (f32x4){0.f, 0.f, 0.f, 0.f};
    auto cluster = [&](const f16x8* AF, const f16x8* BF) {
        #pragma unroll
        for (int jt = 0; jt < 2; ++jt)
            #pragma unroll
            for (int nt = 0; nt < 4; ++nt)
                acc[jt][nt] = __builtin_amdgcn_mfma_f32_16x16x32_f16(AF[jt], BF[nt], acc[jt][nt], 0, 0, 0);
    };

    // ---- GEMM 1: A2 = H1 @ W2 ----
    {
        f16x8 aA[2], bA[4], aB[2], bB[4];
        aload(aA, 0); bloadT(bA, 0);
        #pragma unroll 1
        for (int ks = 0; ks < 16; ks += 2) {
            aload(aB, ks + 1); bloadT(bB, ks + 1);
            cluster(aA, bA);
            if (ks + 2 < 16) { aload(aA, ks + 2); bloadT(bA, ks + 2); }
            cluster(aB, bB);
        }
    }

    // ---- epilogue 1: h2 -> v2 (regs), c (global) ----
    float v2v[2][4][4];
    #pragma unroll
    for (int nt = 0; nt < 4; ++nt) {
        const int mcol = n0 + nt * 16 + l15;
        const float bb = b2[mcol], w3 = W3[mcol];
        #pragma unroll
        for (int jt = 0; jt < 2; ++jt) {
            #pragma unroll
            for (int r = 0; r < 4; ++r) {
                const int srow = jt * 16 + qd * 4 + r;
                const float h2 = tanhf(acc[jt][nt][r] + bb);
                const float t2 = 1.f - h2 * h2;
                const float v2 = w3 * t2;
                v2v[jt][nt][r] = v2;
                g_c[(size_t)(b0 + srow) * HID + mcol] = -2.f * h2 * v2;
            }
        }
    }
    __syncthreads();   // all h1 reads done

    // ---- re-stage alds with V2 ----
    #pragma unroll
    for (int nt = 0; nt < 4; ++nt) {
        const int mcol = n0 + nt * 16 + l15;
        #pragma unroll
        for (int jt = 0; jt < 2; ++jt) {
            #pragma unroll
            for (int r = 0; r < 4; ++r) {
                const int srow = jt * 16 + qd * 4 + r;
                alds[srow * HID + (((mcol >> 3) ^ (srow & 7)) << 3) + (mcol & 7)] = (f16)v2v[jt][nt][r];
            }
        }
    }
    __syncthreads();

    // ---- GEMM 2: U = V2 @ W2^T ----
    #pragma unroll
    for (int a = 0; a < 2; ++a)
        #pragma unroll
        for (int c = 0; c < 4; ++c) acc[a][c] = (f32x4){0.f, 0.f, 0.f, 0.f};
    {
        f16x8 aA[2], bA[4], aB[2], bB[4];
        aload(aA, 0); bloadR(bA, 0);
        #pragma unroll 1
        for (int ms = 0; ms < 16; ms += 2) {
            aload(aB, ms + 1); bloadR(bB, ms + 1);
            cluster(aA, bA);
            if (ms + 2 < 16) { aload(aA, ms + 2); bloadR(bA, ms + 2); }
            cluster(aB, bB);
        }
    }

    // ---- epilogue 2: s = (-2 h1 t1) * u ----
    #pragma unroll
    for (int nt = 0; nt < 4; ++nt) {
        const int kcol = n0 + nt * 16 + l15;
        #pragma unroll
        for (int jt = 0; jt < 2; ++jt) {
            #pragma unroll
            for (int r = 0; r < 4; ++r) {
                const int srow = jt * 16 + qd * 4 + r;
                const size_t idx = (size_t)(b0 + srow) * HID + kcol;
                g_s[idx] = g_n2h1t1[idx] * acc[jt][nt][r];
            }
        }
    }
}

// ---------------- fwd4: term2 = s @ G^T  ([32-sample tile] -> [128 j]) ----------------
__global__ __launch_bounds__(NT)
void fwd4() {
    __shared__ f16 alds[SPB2 * HID];
    const int b0 = blockIdx.x * SPB2;
    const int tid = threadIdx.x, lane = tid & 63, wv = tid >> 6;
    const int l15 = lane & 15, qd = lane >> 4;
    {
        const int sr = tid >> 4;
        f16x8* a8 = (f16x8*)alds;
        #pragma unroll
        for (int c = 0; c < 4; ++c) {
            const int kc = (tid & 15) + c * 16;
            const float* sp = &g_s[(size_t)(b0 + sr) * HID + kc * 8];
            f16x8 h;
            #pragma unroll
            for (int e = 0; e < 8; ++e) h[e] = (f16)sp[e];
            a8[sr * 64 + (kc ^ (sr & 7))] = h;
        }
    }
    __syncthreads();
    f32x4 acc[2];
    acc[0] = (f32x4){0.f, 0.f, 0.f, 0.f};
    acc[1] = (f32x4){0.f, 0.f, 0.f, 0.f};
    const f16x8* a8 = (const f16x8*)alds;
    #pragma unroll 2
    for (int ks = 0; ks < 16; ++ks) {
        f16x8 afr[2], bfr;
        #pragma unroll
        for (int jt = 0; jt < 2; ++jt) {
            const int row = jt * 16 + l15;
            afr[jt] = a8[row * 64 + ((ks * 4 + qd) ^ (row & 7))];
        }
        bfr = *(const f16x8*)&g_Gfrag[(size_t)(((wv * 16 + ks) * 64) + lane) * 8];
        #pragma unroll
        for (int jt = 0; jt < 2; ++jt)
            acc[jt] = __builtin_amdgcn_mfma_f32_16x16x32_f16(afr[jt], bfr, acc[jt], 0, 0, 0);
    }
    const int jc = wv * 16 + l15;
    #pragma unroll
    for (int jt = 0; jt < 2; ++jt)
        #pragma unroll
        for (int r = 0; r < 4; ++r) {
            const int srow = jt * 16 + qd * 4 + r;
            g_t2[(size_t)(b0 + srow) * 128 + jc] = acc[jt][r];
        }
}

// ---------------- main: 2 samples/block, Et-GEMM -> F -> Rt-GEMM -> coalesced fold ----------------
__global__ __launch_bounds__(NT, 2)   // cap 256 regs total (VGPR+AGPR): no spill
void hnn_main(const float* __restrict__ W1, float* __restrict__ out) {
    __shared__ f16 awF[SPB][NQ * HID];       // 128KB: aw (=W1_x*t1), then F (=E*c)
    __shared__ float t1s[SPB][HID], cs[SPB][HID];
    __shared__ float red[SPB][8][NQ][2];     // per-wave partials (no atomics)

    const int tid = threadIdx.x, lane = tid & 63, wv = tid >> 6;
    const int l15 = lane & 15, qd = lane >> 4;
    const int b0 = blockIdx.x * SPB;

    #pragma unroll
    for (int s = 0; s < SPB; ++s) {
        t1s[s][tid] = g_t1[(size_t)(b0 + s) * HID + tid];
        cs[s][tid]  = g_c[(size_t)(b0 + s) * HID + tid];
    }

    // build aw[s][j][k] = W1[x_j,k] * t1[s][k] — coalesced; W1 row read once for both samples
    {
        const int col0 = lane * 8;
        const float4 ta0 = *(const float4*)&g_t1[(size_t)(b0 + 0) * HID + col0];
        const float4 tb0 = *(const float4*)&g_t1[(size_t)(b0 + 0) * HID + col0 + 4];
        const float4 ta1 = *(const float4*)&g_t1[(size_t)(b0 + 1) * HID + col0];
        const float4 tb1 = *(const float4*)&g_t1[(size_t)(b0 + 1) * HID + col0 + 4];
        f16x8* aw80 = (f16x8*)awF[0];
        f16x8* aw81 = (f16x8*)awF[1];
        #pragma unroll
        for (int jr = 0; jr < 8; ++jr) {
            const int j = wv * 8 + jr;
            const float4 wa = *(const float4*)&W1[(size_t)j * HID + col0];
            const float4 wb = *(const float4*)&W1[(size_t)j * HID + col0 + 4];
            f16x8 h0, h1v;
            h0[0] = (f16)(wa.x * ta0.x); h0[1] = (f16)(wa.y * ta0.y);
            h0[2] = (f16)(wa.z * ta0.z); h0[3] = (f16)(wa.w * ta0.w);
            h0[4] = (f16)(wb.x * tb0.x); h0[5] = (f16)(wb.y * tb0.y);
            h0[6] = (f16)(wb.z * tb0.z); h0[7] = (f16)(wb.w * tb0.w);
            h1v[0] = (f16)(wa.x * ta1.x); h1v[1] = (f16)(wa.y * ta1.y);
            h1v[2] = (f16)(wa.z * ta1.z); h1v[3] = (f16)(wa.w * ta1.w);
            h1v[4] = (f16)(wb.x * tb1.x); h1v[5] = (f16)(wb.y * tb1.y);
            h1v[6] = (f16)(wb.z * tb1.z); h1v[7] = (f16)(wb.w * tb1.w);
            aw80[j * 64 + (lane ^ (j & 7))] = h0;
            aw81[j * 64 + (lane ^ (j & 7))] = h1v;
        }
    }
    __syncthreads();

    const int n0 = wv * 64;
    f32x4 acc4[SPB][4][4];
    #pragma unroll
    for (int s = 0; s < SPB; ++s)
        #pragma unroll
        for (int a = 0; a < 4; ++a)
            #pragma unroll
            for (int c = 0; c < 4; ++c) acc4[s][a][c] = (f32x4){0.f, 0.f, 0.f, 0.f};

    auto xloadS = [&](f16x8* XF, int kn, int s) {
        const f16x8* a8 = (const f16x8*)awF[s];
        #pragma unroll
        for (int jt = 0; jt < 4; ++jt) {
            const int row = jt * 16 + l15;
            XF[jt] = a8[row * 64 + ((kn * 4 + qd) ^ (row & 7))];
        }
    };
    auto wloadT = [&](f16x8* WF, int kn) {
        #pragma unroll
        for (int nt = 0; nt < 4; ++nt)
            WF[nt] = *(const f16x8*)&g_w2fragT[(size_t)((((wv * 4 + nt) * 16 + kn) * 64) + lane) * 8];
    };
    auto wloadR = [&](f16x8* WF, int kn) {
        #pragma unroll
        for (int nt = 0; nt < 4; ++nt)
            WF[nt] = *(const f16x8*)&g_w2fragR[(size_t)((((wv * 4 + nt) * 16 + kn) * 64) + lane) * 8];
    };
    // Et cluster: Et[m][j] += W2T-frag[m] * aw-frag[j]
    auto clusterE = [&](const f16x8* WF, const f16x8* XF, int s) {
        #pragma unroll
        for (int mt = 0; mt < 4; ++mt)
            #pragma unroll
            for (int jt = 0; jt < 4; ++jt)
                acc4[s][mt][jt] = __builtin_amdgcn_mfma_f32_16x16x32_f16(WF[mt], XF[jt], acc4[s][mt][jt], 0, 0, 0);
    };
    // Rt cluster: Rt[k][j] += W2R-frag[k] * F-frag[j]  (same A=global/B=LDS structure)
    auto clusterRt = [&](const f16x8* WF, const f16x8* XF, int s) {
        #pragma unroll
        for (int nt = 0; nt < 4; ++nt)
            #pragma unroll
            for (int jt = 0; jt < 4; ++jt)
                acc4[s][nt][jt] = __builtin_amdgcn_mfma_f32_16x16x32_f16(WF[nt], XF[jt], acc4[s][nt][jt], 0, 0, 0);
    };

    // ---- E GEMM (transposed): Et[s][m][j] ----
    {
        f16x8 xP[4], xQ[4], wA[4], wB[4];
        xloadS(xP, 0, 0); wloadT(wA, 0);
        #pragma unroll 1
        for (int ks = 0; ks < 16; ks += 2) {
            xloadS(xQ, ks, 1);
            wloadT(wB, ks + 1);
            clusterE(wA, xP, 0);
            xloadS(xP, ks + 1, 0);
            clusterE(wA, xQ, 1);
            xloadS(xQ, ks + 1, 1);
            if (ks + 2 < 16) wloadT(wA, ks + 2);
            clusterE(wB, xP, 0);
            if (ks + 2 < 16) xloadS(xP, ks + 2, 0);
            clusterE(wB, xQ, 1);
        }
    }
    __syncthreads();

    // ---- F[j][m] = Et[m][j] * c[m], vectorized f16x4 writes ----
    #pragma unroll
    for (int s = 0; s < SPB; ++s) {
        #pragma unroll
        for (int mt = 0; mt < 4; ++mt) {
            const int mbase = n0 + mt * 16 + qd * 4;
            const float4 cv = *(const float4*)&cs[s][mbase];
            const int chunk = mbase >> 3;
            const int half4 = (mbase >> 2) & 1;
            #pragma unroll
            for (int jt = 0; jt < 4; ++jt) {
                const int j = jt * 16 + l15;
                f16x4 h;
                h[0] = (f16)(acc4[s][mt][jt][0] * cv.x);
                h[1] = (f16)(acc4[s][mt][jt][1] * cv.y);
                h[2] = (f16)(acc4[s][mt][jt][2] * cv.z);
                h[3] = (f16)(acc4[s][mt][jt][3] * cv.w);
                *(f16x4*)&awF[s][j * HID + ((chunk ^ (j & 7)) << 3) + half4 * 4] = h;
            }
        }
    }
    __syncthreads();

    // ---- Rt GEMM: Rt[s][64 k][64 j] per wave (k in n0..n0+63) ----
    #pragma unroll
    for (int s = 0; s < SPB; ++s)
        #pragma unroll
        for (int a = 0; a < 4; ++a)
            #pragma unroll
            for (int c = 0; c < 4; ++c) acc4[s][a][c] = (f32x4){0.f, 0.f, 0.f, 0.f};
    {
        f16x8 xP[4], xQ[4], wA[4], wB[4];
        xloadS(xP, 0, 0); wloadR(wA, 0);
        #pragma unroll 1
        for (int ms = 0; ms < 16; ms += 2) {
            xloadS(xQ, ms, 1);
            wloadR(wB, ms + 1);
            clusterRt(wA, xP, 0);
            xloadS(xP, ms + 1, 0);
            clusterRt(wA, xQ, 1);
            xloadS(xQ, ms + 1, 1);
            if (ms + 2 < 16) wloadR(wA, ms + 2);
            clusterRt(wB, xP, 0);
            if (ms + 2 < 16) xloadS(xP, ms + 2, 0);
            clusterRt(wB, xQ, 1);
        }
    }

    // ---- coalesced fold: thread holds k = n0+nt*16+qd*4+r (contiguous in r), j = jt*16+l15 ----
    // vq[j] += W1q[j,k] * t1[k] * Rt[k][j]; k-reduction = in-thread (nt,r) + shfl over qd (2 hops)
    f32x4 t1k[SPB][4];
    #pragma unroll
    for (int s = 0; s < SPB; ++s)
        #pragma unroll
        for (int nt = 0; nt < 4; ++nt)
            t1k[s][nt] = *(const f32x4*)&t1s[s][n0 + nt * 16 + qd * 4];
    #pragma unroll
    for (int jt = 0; jt < 4; ++jt) {
        const int j = jt * 16 + l15;
        const float* w1qrow = &W1[(size_t)(NQ + j) * HID];
        const float* w1prow = &W1[(size_t)(2 * NQ + j) * HID];
        float vq0 = 0.f, vp0 = 0.f, vq1 = 0.f, vp1 = 0.f;
        #pragma unroll
        for (int nt = 0; nt < 4; ++nt) {
            const int kb = n0 + nt * 16 + qd * 4;
            const f32x4 wq = *(const f32x4*)&w1qrow[kb];
            const f32x4 wp = *(const f32x4*)&w1prow[kb];
            #pragma unroll
            for (int r = 0; r < 4; ++r) {
                const float b0v = acc4[0][nt][jt][r] * t1k[0][nt][r];
                const float b1v = acc4[1][nt][jt][r] * t1k[1][nt][r];
                vq0 += wq[r] * b0v; vp0 += wp[r] * b0v;
                vq1 += wq[r] * b1v; vp1 += wp[r] * b1v;
            }
        }
        vq0 += __shfl_xor(vq0, 16, 64); vq0 += __shfl_xor(vq0, 32, 64);
        vp0 += __shfl_xor(vp0, 16, 64); vp0 += __shfl_xor(vp0, 32, 64);
        vq1 += __shfl_xor(vq1, 16, 64); vq1 += __shfl_xor(vq1, 32, 64);
        vp1 += __shfl_xor(vp1, 16, 64); vp1 += __shfl_xor(vp1, 32, 64);
        if (qd == 0) {
            red[0][wv][j][0] = vq0;
            red[0][wv][j][1] = vp0;
            red[1][wv][j][0] = vq1;
            red[1][wv][j][1] = vp1;
        }
    }
    __syncthreads();

    if (tid < SPB * NQ * 2) {
        const int s = tid >> 7, j = (tid >> 1) & 63, c = tid & 1;
        float v = 0.f;
        #pragma unroll
        for (int w = 0; w < 8; ++w) v += red[s][w][j][c];
        v += g_t2[(size_t)(b0 + s) * 128 + c * 64 + j];
        if (c == 0) out[(size_t)BATCH * NQ + (size_t)(b0 + s) * NQ + j] = -v;  // p_dot = -dH_dq_dx
        else        out[(size_t)(b0 + s) * NQ + j] = -v;                       // q_dot = -dH_dp_dx
    }
}

extern "C" void kernel_launch(void* const* d_in, const int* in_sizes, int n_in,
                              void* d_out, int out_size, void* d_ws, size_t ws_size,
                              hipStream_t stream) {
    const float* x  = (const float*)d_in[0];
    const float* q  = (const float*)d_in[1];
    const float* p  = (const float*)d_in[2];
    const float* W1 = (const float*)d_in[3];
    const float* b1 = (const float*)d_in[4];
    const float* W2 = (const float*)d_in[5];
    const float* b2 = (const float*)d_in[6];
    const float* W3 = (const float*)d_in[7];
    float* out = (float*)d_out;

    prep_frag<<<HID, HID, 0, stream>>>(W2);
    prep_g<<<128, HID, 0, stream>>>(W1);
    fwd1<<<BATCH / SPB1, NT, 0, stream>>>(x, q, p, W1, b1);
    fwd23<<<BATCH / SPB2, NT, 0, stream>>>(b2, W3);
    fwd4<<<BATCH / SPB2, NT, 0, stream>>>();
    hnn_main<<<BATCH / SPB, NT, 0, stream>>>(W1, out);
}

// Round 14
// 595.533 us; speedup vs baseline: 1.3123x; 1.0008x over previous
//
#include <hip/hip_runtime.h>

#define BATCH 8192
#define NQ 64          // spatial dim n
#define HID 512
#define DIN 192        // 3*n
#define NT 512         // threads per block (8 waves)
#define SPB1 16        // samples per block, fwd1
#define SPB2 32        // samples per block, fwd234
#define SPB 2          // samples per block, main

typedef _Float16 f16;
typedef _Float16 f16x8 __attribute__((ext_vector_type(8)));
typedef _Float16 f16x4 __attribute__((ext_vector_type(4)));
typedef float f32x4 __attribute__((ext_vector_type(4)));

// W2 in MFMA-fragment-major order (pre-swizzled global, coalesced 1KB frag loads)
__device__ f16 g_w2fragT[HID * HID];  // frag for contraction k
__device__ f16 g_w2fragR[HID * HID];  // frag for contraction m
__device__ f16 g_Gfrag[128 * HID];    // B-frag for term2: G[j,k]=W1q/p[j,k]*W1x[j,k]
// per-sample forward intermediates
__device__ f16   g_h1[(size_t)BATCH * HID];
__device__ float g_t1[(size_t)BATCH * HID];
__device__ float g_n2h1t1[(size_t)BATCH * HID];
__device__ float g_c[(size_t)BATCH * HID];
__device__ float g_t2[(size_t)BATCH * 128];   // term2: cols 0-63 = q, 64-127 = p

// ---------------- prep: fragment-major f16 W2 layouts ----------------
__global__ void prep_frag(const float* __restrict__ W2) {
    const int k = blockIdx.x;    // 512
    const int m = threadIdx.x;   // 512
    const f16 v = (f16)W2[k * HID + m];
    g_w2fragT[(size_t)((((m >> 4) * 16 + (k >> 5)) * 64) + ((m & 15) | (((k >> 3) & 3) << 4))) * 8 + (k & 7)] = v;
    g_w2fragR[(size_t)((((k >> 4) * 16 + (m >> 5)) * 64) + ((k & 15) | (((m >> 3) & 3) << 4))) * 8 + (m & 7)] = v;
}

// ---------------- prep: G fragments (term2 weights, sample-independent) ----------------
__global__ void prep_g(const float* __restrict__ W1) {
    const int j = blockIdx.x;    // 128
    const int k = threadIdx.x;   // 512
    const int jj = j & 63;
    const float w = (j < 64)
        ? W1[(64 + jj) * HID + k] * W1[jj * HID + k]     // G_q
        : W1[(128 + jj) * HID + k] * W1[jj * HID + k];   // G_p
    g_Gfrag[(size_t)((((j >> 4) * 16 + (k >> 5)) * 64) + ((j & 15) | (((k >> 3) & 3) << 4))) * 8 + (k & 7)] = (f16)w;
}

// ---------------- fwd1: layer1 in fp32, batched over samples ----------------
__global__ __launch_bounds__(NT)
void fwd1(const float* __restrict__ x, const float* __restrict__ q,
          const float* __restrict__ p, const float* __restrict__ W1,
          const float* __restrict__ b1) {
    __shared__ float zs[SPB1][DIN];
    const int b0 = blockIdx.x * SPB1;
    const int tid = threadIdx.x;
    for (int i = tid; i < SPB1 * DIN; i += NT) {
        const int s = i / DIN, kk = i % DIN;
        float v;
        if (kk < NQ)          v = x[(b0 + s) * NQ + kk];
        else if (kk < 2 * NQ) v = q[(b0 + s) * NQ + kk - NQ];
        else                  v = p[(b0 + s) * NQ + kk - 2 * NQ];
        zs[s][kk] = v;
    }
    __syncthreads();
    const int m = tid;
    float acc[SPB1];
    #pragma unroll
    for (int s = 0; s < SPB1; ++s) acc[s] = 0.f;
    #pragma unroll 2
    for (int k = 0; k < DIN; ++k) {
        const float w = W1[k * HID + m];
        #pragma unroll
        for (int s = 0; s < SPB1; ++s) acc[s] += zs[s][k] * w;
    }
    const float bb = b1[m];
    #pragma unroll
    for (int s = 0; s < SPB1; ++s) {
        const float h1 = tanhf(acc[s] + bb);
        const float t1 = 1.f - h1 * h1;
        const size_t idx = (size_t)(b0 + s) * HID + m;
        g_h1[idx] = (f16)h1;
        g_t1[idx] = t1;
        g_n2h1t1[idx] = -2.f * h1 * t1;
    }
}

// ---------------- fwd234: H2/v2/c -> U=V2@W2^T -> s -> term2=s@G^T, all fused ----------------
__global__ __launch_bounds__(NT)
void fwd234(const float* __restrict__ b2, const float* __restrict__ W3) {
    __shared__ f16 alds[SPB2 * HID];
    const int b0 = blockIdx.x * SPB2;
    const int tid = threadIdx.x, lane = tid & 63, wv = tid >> 6;
    const int l15 = lane & 15, qd = lane >> 4;
    const int n0 = wv * 64;

    // ---- stage h1 tile ----
    {
        const int s = tid >> 4;
        f16x8* a8 = (f16x8*)alds;
        #pragma unroll
        for (int c = 0; c < 4; ++c) {
            const int kc = (tid & 15) + c * 16;
            const f16x8 v = *(const f16x8*)&g_h1[(size_t)(b0 + s) * HID + kc * 8];
            a8[s * 64 + (kc ^ (s & 7))] = v;
        }
    }
    __syncthreads();

    const f16x8* a8 = (const f16x8*)alds;
    auto aload = [&](f16x8* AF, int kn) {
        #pragma unroll
        for (int jt = 0; jt < 2; ++jt) {
            const int row = jt * 16 + l15;
            AF[jt] = a8[row * 64 + ((kn * 4 + qd) ^ (row & 7))];
        }
    };
    auto bloadT = [&](f16x8* BF, int kn) {
        #pragma unroll
        for (int nt = 0; nt < 4; ++nt)
            BF[nt] = *(const f16x8*)&g_w2fragT[(size_t)((((wv * 4 + nt) * 16 + kn) * 64) + lane) * 8];
    };
    auto bloadR = [&](f16x8* BF, int kn) {
        #pragma unroll
        for (int nt = 0; nt < 4; ++nt)
            BF[nt] = *(const f16x8*)&g_w2fragR[(size_t)((((wv * 4 + nt) * 16 + kn) * 64) + lane) * 8];
    };

    f32x4 acc[2][4];
    #pragma unroll
    for (int a = 0; a < 2; ++a)
        #pragma unroll
        for (int c = 0; c < 4; ++c) acc[a][c] = (f32x4){0.f, 0.f, 0.f, 0.f};
    auto cluster = [&](const f16x8* AF, const f16x8* BF) {
        #pragma unroll
        for (int jt = 0; jt < 2; ++jt)
            #pragma unroll
            for (int nt = 0; nt < 4; ++nt)
                acc[jt][nt] = __builtin_amdgcn_mfma_f32_16x16x32_f16(AF[jt], BF[nt], acc[jt][nt], 0, 0, 0);
    };

    // ---- GEMM 1: A2 = H1 @ W2 ----
    {
        f16x8 aA[2], bA[4], aB[2], bB[4];
        aload(aA, 0); bloadT(bA, 0);
        #pragma unroll 1
        for (int ks = 0; ks < 16; ks += 2) {
            aload(aB, ks + 1); bloadT(bB, ks + 1);
            cluster(aA, bA);
            if (ks + 2 < 16) { aload(aA, ks + 2); bloadT(bA, ks + 2); }
            cluster(aB, bB);
        }
    }

    // ---- epilogue 1: h2 -> v2 (regs), c (global) ----
    float v2v[2][4][4];
    #pragma unroll
    for (int nt = 0; nt < 4; ++nt) {
        const int mcol = n0 + nt * 16 + l15;
        const float bb = b2[mcol], w3 = W3[mcol];
        #pragma unroll
        for (int jt = 0; jt < 2; ++jt) {
            #pragma unroll
            for (int r = 0; r < 4; ++r) {
                const int srow = jt * 16 + qd * 4 + r;
                const float h2 = tanhf(acc[jt][nt][r] + bb);
                const float t2 = 1.f - h2 * h2;
                const float v2 = w3 * t2;
                v2v[jt][nt][r] = v2;
                g_c[(size_t)(b0 + srow) * HID + mcol] = -2.f * h2 * v2;
            }
        }
    }
    __syncthreads();   // all h1 reads done

    // ---- re-stage alds with V2 ----
    #pragma unroll
    for (int nt = 0; nt < 4; ++nt) {
        const int mcol = n0 + nt * 16 + l15;
        #pragma unroll
        for (int jt = 0; jt < 2; ++jt) {
            #pragma unroll
            for (int r = 0; r < 4; ++r) {
                const int srow = jt * 16 + qd * 4 + r;
                alds[srow * HID + (((mcol >> 3) ^ (srow & 7)) << 3) + (mcol & 7)] = (f16)v2v[jt][nt][r];
            }
        }
    }
    __syncthreads();

    // ---- GEMM 2: U = V2 @ W2^T ----
    #pragma unroll
    for (int a = 0; a < 2; ++a)
        #pragma unroll
        for (int c = 0; c < 4; ++c) acc[a][c] = (f32x4){0.f, 0.f, 0.f, 0.f};
    {
        f16x8 aA[2], bA[4], aB[2], bB[4];
        aload(aA, 0); bloadR(bA, 0);
        #pragma unroll 1
        for (int ms = 0; ms < 16; ms += 2) {
            aload(aB, ms + 1); bloadR(bB, ms + 1);
            cluster(aA, bA);
            if (ms + 2 < 16) { aload(aA, ms + 2); bloadR(bA, ms + 2); }
            cluster(aB, bB);
        }
    }
    __syncthreads();   // all V2 reads done before s overwrites alds

    // ---- epilogue 2: s = (-2 h1 t1) * u  -> re-stage into alds (f16, swizzled) ----
    #pragma unroll
    for (int nt = 0; nt < 4; ++nt) {
        const int kcol = n0 + nt * 16 + l15;
        #pragma unroll
        for (int jt = 0; jt < 2; ++jt) {
            #pragma unroll
            for (int r = 0; r < 4; ++r) {
                const int srow = jt * 16 + qd * 4 + r;
                const size_t idx = (size_t)(b0 + srow) * HID + kcol;
                const float sval = g_n2h1t1[idx] * acc[jt][nt][r];
                alds[srow * HID + (((kcol >> 3) ^ (srow & 7)) << 3) + (kcol & 7)] = (f16)sval;
            }
        }
    }
    __syncthreads();

    // ---- GEMM 3 (was fwd4): term2 = s @ G^T ----
    f32x4 acc2[2];
    acc2[0] = (f32x4){0.f, 0.f, 0.f, 0.f};
    acc2[1] = (f32x4){0.f, 0.f, 0.f, 0.f};
    #pragma unroll 2
    for (int ks = 0; ks < 16; ++ks) {
        f16x8 afr[2], bfr;
        #pragma unroll
        for (int jt = 0; jt < 2; ++jt) {
            const int row = jt * 16 + l15;
            afr[jt] = a8[row * 64 + ((ks * 4 + qd) ^ (row & 7))];
        }
        bfr = *(const f16x8*)&g_Gfrag[(size_t)(((wv * 16 + ks) * 64) + lane) * 8];
        #pragma unroll
        for (int jt = 0; jt < 2; ++jt)
            acc2[jt] = __builtin_amdgcn_mfma_f32_16x16x32_f16(afr[jt], bfr, acc2[jt], 0, 0, 0);
    }
    const int jc = wv * 16 + l15;
    #pragma unroll
    for (int jt = 0; jt < 2; ++jt)
        #pragma unroll
        for (int r = 0; r < 4; ++r) {
            const int srow = jt * 16 + qd * 4 + r;
            g_t2[(size_t)(b0 + srow) * 128 + jc] = acc2[jt][r];
        }
}

// ---------------- main: 2 samples/block, Et-GEMM -> F -> Rt-GEMM -> coalesced fold ----------------
__global__ __launch_bounds__(NT, 2)   // cap 256 regs total (VGPR+AGPR): no spill
void hnn_main(const float* __restrict__ W1, float* __restrict__ out) {
    __shared__ f16 awF[SPB][NQ * HID];       // 128KB: aw (=W1_x*t1), then F (=E*c)
    __shared__ float t1s[SPB][HID], cs[SPB][HID];
    __shared__ float red[SPB][8][NQ][2];     // per-wave partials (no atomics)

    const int tid = threadIdx.x, lane = tid & 63, wv = tid >> 6;
    const int l15 = lane & 15, qd = lane >> 4;
    const int b0 = blockIdx.x * SPB;

    #pragma unroll
    for (int s = 0; s < SPB; ++s) {
        t1s[s][tid] = g_t1[(size_t)(b0 + s) * HID + tid];
        cs[s][tid]  = g_c[(size_t)(b0 + s) * HID + tid];
    }

    // build aw[s][j][k] = W1[x_j,k] * t1[s][k] — coalesced; W1 row read once for both samples
    {
        const int col0 = lane * 8;
        const float4 ta0 = *(const float4*)&g_t1[(size_t)(b0 + 0) * HID + col0];
        const float4 tb0 = *(const float4*)&g_t1[(size_t)(b0 + 0) * HID + col0 + 4];
        const float4 ta1 = *(const float4*)&g_t1[(size_t)(b0 + 1) * HID + col0];
        const float4 tb1 = *(const float4*)&g_t1[(size_t)(b0 + 1) * HID + col0 + 4];
        f16x8* aw80 = (f16x8*)awF[0];
        f16x8* aw81 = (f16x8*)awF[1];
        #pragma unroll
        for (int jr = 0; jr < 8; ++jr) {
            const int j = wv * 8 + jr;
            const float4 wa = *(const float4*)&W1[(size_t)j * HID + col0];
            const float4 wb = *(const float4*)&W1[(size_t)j * HID + col0 + 4];
            f16x8 h0, h1v;
            h0[0] = (f16)(wa.x * ta0.x); h0[1] = (f16)(wa.y * ta0.y);
            h0[2] = (f16)(wa.z * ta0.z); h0[3] = (f16)(wa.w * ta0.w);
            h0[4] = (f16)(wb.x * tb0.x); h0[5] = (f16)(wb.y * tb0.y);
            h0[6] = (f16)(wb.z * tb0.z); h0[7] = (f16)(wb.w * tb0.w);
            h1v[0] = (f16)(wa.x * ta1.x); h1v[1] = (f16)(wa.y * ta1.y);
            h1v[2] = (f16)(wa.z * ta1.z); h1v[3] = (f16)(wa.w * ta1.w);
            h1v[4] = (f16)(wb.x * tb1.x); h1v[5] = (f16)(wb.y * tb1.y);
            h1v[6] = (f16)(wb.z * tb1.z); h1v[7] = (f16)(wb.w * tb1.w);
            aw80[j * 64 + (lane ^ (j & 7))] = h0;
            aw81[j * 64 + (lane ^ (j & 7))] = h1v;
        }
    }
    __syncthreads();

    const int n0 = wv * 64;
    f32x4 acc4[SPB][4][4];
    #pragma unroll
    for (int s = 0; s < SPB; ++s)
        #pragma unroll
        for (int a = 0; a < 4; ++a)
            #pragma unroll
            for (int c = 0; c < 4; ++c) acc4[s][a][c] = (f32x4){0.f, 0.f, 0.f, 0.f};

    auto xloadS = [&](f16x8* XF, int kn, int s) {
        const f16x8* a8 = (const f16x8*)awF[s];
        #pragma unroll
        for (int jt = 0; jt < 4; ++jt) {
            const int row = jt * 16 + l15;
            XF[jt] = a8[row * 64 + ((kn * 4 + qd) ^ (row & 7))];
        }
    };
    auto wloadT = [&](f16x8* WF, int kn) {
        #pragma unroll
        for (int nt = 0; nt < 4; ++nt)
            WF[nt] = *(const f16x8*)&g_w2fragT[(size_t)((((wv * 4 + nt) * 16 + kn) * 64) + lane) * 8];
    };
    auto wloadR = [&](f16x8* WF, int kn) {
        #pragma unroll
        for (int nt = 0; nt < 4; ++nt)
            WF[nt] = *(const f16x8*)&g_w2fragR[(size_t)((((wv * 4 + nt) * 16 + kn) * 64) + lane) * 8];
    };
    // Et cluster: Et[m][j] += W2T-frag[m] * aw-frag[j]
    auto clusterE = [&](const f16x8* WF, const f16x8* XF, int s) {
        #pragma unroll
        for (int mt = 0; mt < 4; ++mt)
            #pragma unroll
            for (int jt = 0; jt < 4; ++jt)
                acc4[s][mt][jt] = __builtin_amdgcn_mfma_f32_16x16x32_f16(WF[mt], XF[jt], acc4[s][mt][jt], 0, 0, 0);
    };
    // Rt cluster: Rt[k][j] += W2R-frag[k] * F-frag[j]
    auto clusterRt = [&](const f16x8* WF, const f16x8* XF, int s) {
        #pragma unroll
        for (int nt = 0; nt < 4; ++nt)
            #pragma unroll
            for (int jt = 0; jt < 4; ++jt)
                acc4[s][nt][jt] = __builtin_amdgcn_mfma_f32_16x16x32_f16(WF[nt], XF[jt], acc4[s][nt][jt], 0, 0, 0);
    };

    // ---- E GEMM (transposed): Et[s][m][j] ----
    {
        f16x8 xP[4], xQ[4], wA[4], wB[4];
        xloadS(xP, 0, 0); wloadT(wA, 0);
        #pragma unroll 1
        for (int ks = 0; ks < 16; ks += 2) {
            xloadS(xQ, ks, 1);
            wloadT(wB, ks + 1);
            clusterE(wA, xP, 0);
            xloadS(xP, ks + 1, 0);
            clusterE(wA, xQ, 1);
            xloadS(xQ, ks + 1, 1);
            if (ks + 2 < 16) wloadT(wA, ks + 2);
            clusterE(wB, xP, 0);
            if (ks + 2 < 16) xloadS(xP, ks + 2, 0);
            clusterE(wB, xQ, 1);
        }
    }
    __syncthreads();

    // ---- F[j][m] = Et[m][j] * c[m], vectorized f16x4 writes ----
    #pragma unroll
    for (int s = 0; s < SPB; ++s) {
        #pragma unroll
        for (int mt = 0; mt < 4; ++mt) {
            const int mbase = n0 + mt * 16 + qd * 4;
            const float4 cv = *(const float4*)&cs[s][mbase];
            const int chunk = mbase >> 3;
            const int half4 = (mbase >> 2) & 1;
            #pragma unroll
            for (int jt = 0; jt < 4; ++jt) {
                const int j = jt * 16 + l15;
                f16x4 h;
                h[0] = (f16)(acc4[s][mt][jt][0] * cv.x);
                h[1] = (f16)(acc4[s][mt][jt][1] * cv.y);
                h[2] = (f16)(acc4[s][mt][jt][2] * cv.z);
                h[3] = (f16)(acc4[s][mt][jt][3] * cv.w);
                *(f16x4*)&awF[s][j * HID + ((chunk ^ (j & 7)) << 3) + half4 * 4] = h;
            }
        }
    }
    __syncthreads();

    // ---- Rt GEMM: Rt[s][64 k][64 j] per wave (k in n0..n0+63) ----
    #pragma unroll
    for (int s = 0; s < SPB; ++s)
        #pragma unroll
        for (int a = 0; a < 4; ++a)
            #pragma unroll
            for (int c = 0; c < 4; ++c) acc4[s][a][c] = (f32x4){0.f, 0.f, 0.f, 0.f};
    {
        f16x8 xP[4], xQ[4], wA[4], wB[4];
        xloadS(xP, 0, 0); wloadR(wA, 0);
        #pragma unroll 1
        for (int ms = 0; ms < 16; ms += 2) {
            xloadS(xQ, ms, 1);
            wloadR(wB, ms + 1);
            clusterRt(wA, xP, 0);
            xloadS(xP, ms + 1, 0);
            clusterRt(wA, xQ, 1);
            xloadS(xQ, ms + 1, 1);
            if (ms + 2 < 16) wloadR(wA, ms + 2);
            clusterRt(wB, xP, 0);
            if (ms + 2 < 16) xloadS(xP, ms + 2, 0);
            clusterRt(wB, xQ, 1);
        }
    }

    // ---- coalesced fold: thread holds k = n0+nt*16+qd*4+r, j = jt*16+l15 ----
    f32x4 t1k[SPB][4];
    #pragma unroll
    for (int s = 0; s < SPB; ++s)
        #pragma unroll
        for (int nt = 0; nt < 4; ++nt)
            t1k[s][nt] = *(const f32x4*)&t1s[s][n0 + nt * 16 + qd * 4];
    #pragma unroll
    for (int jt = 0; jt < 4; ++jt) {
        const int j = jt * 16 + l15;
        const float* w1qrow = &W1[(size_t)(NQ + j) * HID];
        const float* w1prow = &W1[(size_t)(2 * NQ + j) * HID];
        float vq0 = 0.f, vp0 = 0.f, vq1 = 0.f, vp1 = 0.f;
        #pragma unroll
        for (int nt = 0; nt < 4; ++nt) {
            const int kb = n0 + nt * 16 + qd * 4;
            const f32x4 wq = *(const f32x4*)&w1qrow[kb];
            const f32x4 wp = *(const f32x4*)&w1prow[kb];
            #pragma unroll
            for (int r = 0; r < 4; ++r) {
                const float b0v = acc4[0][nt][jt][r] * t1k[0][nt][r];
                const float b1v = acc4[1][nt][jt][r] * t1k[1][nt][r];
                vq0 += wq[r] * b0v; vp0 += wp[r] * b0v;
                vq1 += wq[r] * b1v; vp1 += wp[r] * b1v;
            }
        }
        vq0 += __shfl_xor(vq0, 16, 64); vq0 += __shfl_xor(vq0, 32, 64);
        vp0 += __shfl_xor(vp0, 16, 64); vp0 += __shfl_xor(vp0, 32, 64);
        vq1 += __shfl_xor(vq1, 16, 64); vq1 += __shfl_xor(vq1, 32, 64);
        vp1 += __shfl_xor(vp1, 16, 64); vp1 += __shfl_xor(vp1, 32, 64);
        if (qd == 0) {
            red[0][wv][j][0] = vq0;
            red[0][wv][j][1] = vp0;
            red[1][wv][j][0] = vq1;
            red[1][wv][j][1] = vp1;
        }
    }
    __syncthreads();

    if (tid < SPB * NQ * 2) {
        const int s = tid >> 7, j = (tid >> 1) & 63, c = tid & 1;
        float v = 0.f;
        #pragma unroll
        for (int w = 0; w < 8; ++w) v += red[s][w][j][c];
        v += g_t2[(size_t)(b0 + s) * 128 + c * 64 + j];
        if (c == 0) out[(size_t)BATCH * NQ + (size_t)(b0 + s) * NQ + j] = -v;  // p_dot = -dH_dq_dx
        else        out[(size_t)(b0 + s) * NQ + j] = -v;                       // q_dot = -dH_dp_dx
    }
}

extern "C" void kernel_launch(void* const* d_in, const int* in_sizes, int n_in,
                              void* d_out, int out_size, void* d_ws, size_t ws_size,
                              hipStream_t stream) {
    const float* x  = (const float*)d_in[0];
    const float* q  = (const float*)d_in[1];
    const float* p  = (const float*)d_in[2];
    const float* W1 = (const float*)d_in[3];
    const float* b1 = (const float*)d_in[4];
    const float* W2 = (const float*)d_in[5];
    const float* b2 = (const float*)d_in[6];
    const float* W3 = (const float*)d_in[7];
    float* out = (float*)d_out;

    prep_frag<<<HID, HID, 0, stream>>>(W2);
    prep_g<<<128, HID, 0, stream>>>(W1);
    fwd1<<<BATCH / SPB1, NT, 0, stream>>>(x, q, p, W1, b1);
    fwd234<<<BATCH / SPB2, NT, 0, stream>>>(b2, W3);
    hnn_main<<<BATCH / SPB, NT, 0, stream>>>(W1, out);
}